// Round 1
// 334.894 us; speedup vs baseline: 1.0611x; 1.0611x over previous
//
#include <hip/hip_runtime.h>
#include <math.h>

#define B_ 2
#define N_ 16384
#define D_ 512
#define C_ 4
#define K_ 8
#define ROWS (B_*N_)      // 32768 rows per side
#define ROWS2 (2*ROWS)    // 65536 rows both sides
#define EPS_ 1e-12f

typedef unsigned short u16;
typedef unsigned int u32;
using short8  = __attribute__((ext_vector_type(8))) short;
using float4v = __attribute__((ext_vector_type(4))) float;

__device__ __forceinline__ u16 f2bf(float f) {
    union { float f; u32 u; } v; v.f = f;
    u32 r = v.u + 0x7fffu + ((v.u >> 16) & 1u);
    return (u16)(r >> 16);
}
__device__ __forceinline__ u32 pack2(float a, float b) {
    return (u32)f2bf(a) | ((u32)f2bf(b) << 16);
}
__device__ __forceinline__ float bf2f(u16 h) {
    union { u32 u; float f; } v; v.u = ((u32)h) << 16;
    return v.f;
}
__device__ __forceinline__ void load_lds16(const u16* g, u16* l) {
    __builtin_amdgcn_global_load_lds(
        (const __attribute__((address_space(1))) u32*)g,
        (__attribute__((address_space(3))) u32*)l, 16, 0, 0);
}
// Stage 8 rows x 64 k (bf16) of a row-major tile (row stride 512 u16) into LDS,
// fully coalesced, XOR-swizzled. LDS addr(r,c)=r*64 + (c^(r&7))*8 (u16).
__device__ __forceinline__ void stage_rows8(const u16* gtile, u16* ldsTile, int g, int lane) {
    int rg = lane >> 3;
    int c  = (lane & 7) ^ rg;
    load_lds16(gtile + (size_t)(g * 8 + rg) * 512 + c * 8, ldsTile + g * 512);
}
#define AFRAG(lds, R, c) (*(const short8*)&(lds)[(R) * 64 + (((c) ^ ((R) & 7)) * 8)])

// ---------------- P0: weight prep ----------------
__global__ __launch_bounds__(256) void prep_weights_kernel(
    const float* __restrict__ Wp, const float* __restrict__ Wv, const float* __restrict__ Wu,
    const float* __restrict__ bv, const float* __restrict__ bu, const float* __restrict__ desc,
    u16* __restrict__ WpT, u16* __restrict__ WvuT, float* __restrict__ bvu,
    u16* __restrict__ descF)
{
    int idx = blockIdx.x * 256 + threadIdx.x;   // 0 .. 262143
    int n = idx >> 9, k = idx & 511;
    WpT[idx] = f2bf(Wp[k * 512 + n]);
    int tile = n >> 4, pair = tile >> 1, half = tile & 1, h = pair * 16 + (n & 15);
    WvuT[idx] = f2bf(half ? Wu[k * 256 + h] : Wv[k * 256 + h]);
    if (idx < 512) {
        int tl = idx >> 4, pr = tl >> 1, hf = tl & 1, hh = pr * 16 + (idx & 15);
        bvu[idx] = hf ? bu[hh] : bv[hh];
    }
    if (idx < 16384) {
        int j = idx & 7, l = (idx >> 3) & 63, g = (idx >> 9) & 1, kt = idx >> 10;
        descF[idx] = f2bf(desc[(size_t)(g * 16 + (l & 15)) * 512 + kt * 32 + (l >> 4) * 8 + j]);
    }
}

// ---------------- K0: per-row L2-normalize x and cast to bf16 (both sides) ----------------
__global__ __launch_bounds__(256) void rownorm_cast_kernel(
    const float* __restrict__ x_s, const float* __restrict__ x_l, u16* __restrict__ xn)
{
    int wave = threadIdx.x >> 6, lane = threadIdx.x & 63;
    size_t row = (size_t)blockIdx.x * 4 + wave;
    const float* xr = (row < (size_t)ROWS) ? (x_s + row * D_)
                                           : (x_l + (row - ROWS) * D_);
    float4 a = *(const float4*)&xr[lane * 8];
    float4 b = *(const float4*)&xr[lane * 8 + 4];
    float s = a.x*a.x + a.y*a.y + a.z*a.z + a.w*a.w
            + b.x*b.x + b.y*b.y + b.z*b.z + b.w*b.w;
#pragma unroll
    for (int off = 32; off; off >>= 1) s += __shfl_xor(s, off, 64);
    float inv = 1.0f / fmaxf(sqrtf(s), EPS_);
    uint4 o;
    o.x = pack2(a.x * inv, a.y * inv);
    o.y = pack2(a.z * inv, a.w * inv);
    o.z = pack2(b.x * inv, b.y * inv);
    o.w = pack2(b.z * inv, b.w * inv);
    *(uint4*)&xn[row * D_ + lane * 8] = o;
}

// ---------------- K1: GEMM xpraw = xn @ WpT^T + bias (full N=512 per block) ---------
__global__ __launch_bounds__(512, 2) void gemm_bias_kernel(
    const u16* __restrict__ A, const u16* __restrict__ Bt,
    const float* __restrict__ bias, u16* __restrict__ C)
{
    __shared__ u16 ldsA[128 * 64];
    __shared__ u16 ldsB[512 * 64];
    int t = threadIdx.x, wave = t >> 6, lane = t & 63;
    int lr = lane & 15, lq = lane >> 4;
    int wm = wave >> 2, wn = wave & 3;
    int M0 = blockIdx.x * 128;

    float4v acc[4][8];
#pragma unroll
    for (int i = 0; i < 4; ++i)
#pragma unroll
        for (int j = 0; j < 8; ++j)
#pragma unroll
            for (int r = 0; r < 4; ++r) acc[i][j][r] = 0.f;

    for (int k0 = 0; k0 < 512; k0 += 64) {
        const u16* Ab = A  + (size_t)M0 * 512 + k0;
        const u16* Bb = Bt + k0;
        stage_rows8(Ab, ldsA, wave * 2 + 0, lane);
        stage_rows8(Ab, ldsA, wave * 2 + 1, lane);
#pragma unroll
        for (int s = 0; s < 8; ++s) stage_rows8(Bb, ldsB, wave * 8 + s, lane);
        __syncthreads();
#pragma unroll
        for (int kt = 0; kt < 2; ++kt) {
            short8 af[4], bfr[8];
#pragma unroll
            for (int i = 0; i < 4; ++i)
                af[i] = AFRAG(ldsA, wm * 64 + i * 16 + lr, kt * 4 + lq);
#pragma unroll
            for (int j = 0; j < 8; ++j)
                bfr[j] = AFRAG(ldsB, wn * 128 + j * 16 + lr, kt * 4 + lq);
#pragma unroll
            for (int i = 0; i < 4; ++i)
#pragma unroll
                for (int j = 0; j < 8; ++j)
                    acc[i][j] = __builtin_amdgcn_mfma_f32_16x16x32_bf16(bfr[j], af[i], acc[i][j], 0, 0, 0);
        }
        __syncthreads();
    }

    int colbase = wn * 128;
    float4 b4[8];
#pragma unroll
    for (int j = 0; j < 8; ++j)
        b4[j] = *(const float4*)&bias[colbase + j * 16 + lq * 4];
#pragma unroll
    for (int i = 0; i < 4; ++i) {
        int m = M0 + wm * 64 + i * 16 + lr;
        u16* crow = C + (size_t)m * 512;
#pragma unroll
        for (int j = 0; j < 8; ++j) {
            int nb = colbase + j * 16 + lq * 4;
            uint2 o;
            o.x = pack2(acc[i][j][0] + b4[j].x, acc[i][j][1] + b4[j].y);
            o.y = pack2(acc[i][j][2] + b4[j].z, acc[i][j][3] + b4[j].w);
            *(uint2*)&crow[nb] = o;
        }
    }
}

// ---------------- K2: fused gate GEMM + class scores + Gram-diag invn ------------
// Full N=512 per block -> gate scalar finished in-block, single Araw slab.
__global__ __launch_bounds__(512, 2) void gatecls_kernel(
    const u16* __restrict__ A, const u16* __restrict__ Bt,
    const u16* __restrict__ descF,
    const float* __restrict__ bvu, const float* __restrict__ w_attn,
    float* __restrict__ invn, float* __restrict__ Araw,
    float* __restrict__ out10)
{
    __shared__ u16 ldsA[128 * 64];
    __shared__ u16 ldsB[512 * 64];
    int t = threadIdx.x, wave = t >> 6, lane = t & 63;
    int lr = lane & 15, lq = lane >> 4;
    int wm = wave >> 2, wn = wave & 3;
    int M0 = blockIdx.x * 128;

    float4v acc[4][8];
    float4v accS[2], accG;
#pragma unroll
    for (int i = 0; i < 4; ++i)
#pragma unroll
        for (int j = 0; j < 8; ++j)
#pragma unroll
            for (int r = 0; r < 4; ++r) acc[i][j][r] = 0.f;
#pragma unroll
    for (int r = 0; r < 4; ++r) { accS[0][r] = 0.f; accS[1][r] = 0.f; accG[r] = 0.f; }

    for (int k0 = 0; k0 < 512; k0 += 64) {
        const u16* Ab = A  + (size_t)M0 * 512 + k0;
        const u16* Bb = Bt + k0;
        stage_rows8(Ab, ldsA, wave * 2 + 0, lane);
        stage_rows8(Ab, ldsA, wave * 2 + 1, lane);
#pragma unroll
        for (int s = 0; s < 8; ++s) stage_rows8(Bb, ldsB, wave * 8 + s, lane);
        __syncthreads();
#pragma unroll
        for (int kt = 0; kt < 2; ++kt) {
            int ktg = (k0 >> 5) + kt;
            // class-score MFMAs on the same staged A tile; desc frags from L2
            short8 d0 = *(const short8*)&descF[(ktg * 2 + 0) * 512 + lane * 8];
            short8 d1 = *(const short8*)&descF[(ktg * 2 + 1) * 512 + lane * 8];
            short8 afc = AFRAG(ldsA, wave * 16 + lr, kt * 4 + lq);
            accS[0] = __builtin_amdgcn_mfma_f32_16x16x32_bf16(afc, d0, accS[0], 0, 0, 0);
            accS[1] = __builtin_amdgcn_mfma_f32_16x16x32_bf16(afc, d1, accS[1], 0, 0, 0);
            accG    = __builtin_amdgcn_mfma_f32_16x16x32_bf16(afc, afc, accG, 0, 0, 0);
            short8 af[4], bfr[8];
#pragma unroll
            for (int i = 0; i < 4; ++i)
                af[i] = AFRAG(ldsA, wm * 64 + i * 16 + lr, kt * 4 + lq);
#pragma unroll
            for (int j = 0; j < 8; ++j)
                bfr[j] = AFRAG(ldsB, wn * 128 + j * 16 + lr, kt * 4 + lq);
#pragma unroll
            for (int i = 0; i < 4; ++i)
#pragma unroll
                for (int j = 0; j < 8; ++j)
                    acc[i][j] = __builtin_amdgcn_mfma_f32_16x16x32_bf16(bfr[j], af[i], acc[i][j], 0, 0, 0);
        }
        __syncthreads();
    }

    // LDS overlay on ldsA (all tile reads are done): 128 invn + 4x128 gate partials
    float* sInvF = (float*)ldsA;            // [128]
    float* redA  = ((float*)ldsA) + 128;    // [4][128]

    // --- invn from Gram diagonal ---
#pragma unroll
    for (int r = 0; r < 4; ++r) {
        if (lr == lq * 4 + r) {
            float iv = 1.0f / fmaxf(sqrtf(accG[r]), EPS_);
            sInvF[wave * 16 + lq * 4 + r] = iv;
            invn[M0 + wave * 16 + lq * 4 + r] = iv;
        }
    }
    __syncthreads();

    // --- class scores (each wave owns 16 rows: wave*16 .. wave*16+15) ---
    {
        const float scale = 0.04419417382415922f;   // 512^-0.5
        int side = (M0 >= ROWS) ? 1 : 0;
        float* cls = out10 + (size_t)side * ((size_t)ROWS * 4);
        int rbase = M0 - side * ROWS + wave * 16;
#pragma unroll
        for (int r = 0; r < 4; ++r) {
            int rloc = rbase + lq * 4 + r;
            float iv = sInvF[wave * 16 + lq * 4 + r];
            float sv0 = accS[0][r] * iv, sv1 = accS[1][r] * iv;
#pragma unroll
            for (int g = 0; g < 2; ++g) {
                float s = g ? sv1 : sv0;
                float ts = s * scale;
                float mx = ts;
                mx = fmaxf(mx, __shfl_xor(mx, 1, 64));
                mx = fmaxf(mx, __shfl_xor(mx, 2, 64));
                mx = fmaxf(mx, __shfl_xor(mx, 4, 64));
                float e = expf(ts - mx);
                float num = e * s, den = e;
                num += __shfl_xor(num, 1, 64); den += __shfl_xor(den, 1, 64);
                num += __shfl_xor(num, 2, 64); den += __shfl_xor(den, 2, 64);
                num += __shfl_xor(num, 4, 64); den += __shfl_xor(den, 4, 64);
                if ((lr & 7) == 0) {
                    int c = g * 2 + ((lr >> 3) & 1);
                    cls[(size_t)rloc * 4 + c] = num / den;
                }
            }
        }
    }

    // --- gated-attention scalar (full row in block) ---
    int colbase = wn * 128;
    int hbase = colbase >> 1;
    float4 bv4[4], bu4[4], w4[4];
#pragma unroll
    for (int p = 0; p < 4; ++p) {
        int nv = colbase + p * 32 + lq * 4;
        bv4[p] = *(const float4*)&bvu[nv];
        bu4[p] = *(const float4*)&bvu[nv + 16];
        w4[p]  = *(const float4*)&w_attn[hbase + p * 16 + lq * 4];
    }
#pragma unroll
    for (int i = 0; i < 4; ++i) {
        int rloc = wm * 64 + i * 16 + lr;
        float iv = sInvF[rloc];
        float part = 0.f;
#pragma unroll
        for (int p = 0; p < 4; ++p) {
#pragma unroll
            for (int r = 0; r < 4; ++r) {
                float v = acc[i][2 * p][r] * iv + (&bv4[p].x)[r];
                float u = acc[i][2 * p + 1][r] * iv + (&bu4[p].x)[r];
                part += tanhf(v) * (&w4[p].x)[r] * (1.0f / (1.0f + expf(-u)));
            }
        }
        part += __shfl_xor(part, 16, 64);
        part += __shfl_xor(part, 32, 64);
        if (lq == 0) redA[wn * 128 + rloc] = part;
    }
    __syncthreads();
    if (t < 128) Araw[M0 + t] = redA[t] + redA[128 + t] + redA[256 + t] + redA[384 + t];
}

// ---------------- K5a: per-block (max, expsum) partials over 4 (side,batch) groups --
// grid (32, 4), 256 thr; block covers 512 rows of group g.
__global__ __launch_bounds__(256) void areduce_kernel(
    const float* __restrict__ Araw, float* __restrict__ part)
{
    __shared__ float red[256];
    int t = threadIdx.x, g = blockIdx.y;
    size_t i0 = (size_t)g * N_ + blockIdx.x * 512 + t * 2;
    float2 v = *(const float2*)&Araw[i0];
    red[t] = fmaxf(v.x, v.y); __syncthreads();
    for (int s = 128; s; s >>= 1) { if (t < s) red[t] = fmaxf(red[t], red[t + s]); __syncthreads(); }
    float m = red[0]; __syncthreads();
    red[t] = __expf(v.x - m) + __expf(v.y - m); __syncthreads();
    for (int s = 128; s; s >>= 1) { if (t < s) red[t] += red[t + s]; __syncthreads(); }
    if (t == 0) {
        int pi = g * 32 + blockIdx.x;
        part[pi * 2] = m;
        part[pi * 2 + 1] = red[0];
    }
}

// ---------------- K5b: combine 32 partials per group -> mg[g] ----------------
__global__ __launch_bounds__(128) void acombine_kernel(
    const float* __restrict__ part, float* __restrict__ mg)
{
    int t = threadIdx.x;              // 0..127, two waves
    int g = t >> 5, j = t & 31;
    float m = part[(g * 32 + j) * 2];
    float s = part[(g * 32 + j) * 2 + 1];
    float mm = m;
#pragma unroll
    for (int off = 1; off < 32; off <<= 1) mm = fmaxf(mm, __shfl_xor(mm, off, 64));
    float sc = s * __expf(m - mm);
#pragma unroll
    for (int off = 1; off < 32; off <<= 1) sc += __shfl_xor(sc, off, 64);
    if (j == 0) {
        mg[g * 2] = mm;
        mg[g * 2 + 1] = 1.0f / sc;
    }
}

// ---------------- K6: pooling with inline softmax normalize ----------------
// grid (64, 4); block 256 = 4 waves; block covers 256 rows of group g.
__global__ __launch_bounds__(256) void pool_kernel(
    const float* __restrict__ Araw, const float* __restrict__ invn,
    const float* __restrict__ mg, const u16* __restrict__ xpraw,
    float* __restrict__ slideAll)
{
    __shared__ float lds[4][512];
    int t = threadIdx.x, wave = t >> 6, lane = t & 63;
    int g = blockIdx.y;
    float m = mg[g * 2], is = mg[g * 2 + 1];
    size_t row0 = (size_t)g * N_ + (size_t)blockIdx.x * 256 + wave;
    float a[8] = {};
    for (int r = 0; r < 64; ++r) {
        size_t row = row0 + r * 4;
        float av = __expf(Araw[row] - m) * is * invn[row];
        uint4 pk = *(const uint4*)&xpraw[row * D_ + lane * 8];
        a[0] += av * bf2f((u16)pk.x); a[1] += av * bf2f((u16)(pk.x >> 16));
        a[2] += av * bf2f((u16)pk.y); a[3] += av * bf2f((u16)(pk.y >> 16));
        a[4] += av * bf2f((u16)pk.z); a[5] += av * bf2f((u16)(pk.z >> 16));
        a[6] += av * bf2f((u16)pk.w); a[7] += av * bf2f((u16)(pk.w >> 16));
    }
#pragma unroll
    for (int i = 0; i < 8; ++i) lds[wave][lane * 8 + i] = a[i];
    __syncthreads();
#pragma unroll
    for (int q = 0; q < 2; ++q) {
        int c = t * 2 + q;
        float s = lds[0][c] + lds[1][c] + lds[2][c] + lds[3][c];
        atomicAdd(&slideAll[(size_t)g * 512 + c], s);
    }
}

// ---------------- K7: finalize ----------------
__global__ __launch_bounds__(512) void finalize_kernel(
    const float* __restrict__ slide_s, const float* __restrict__ slide_l,
    const float* __restrict__ desc, float* __restrict__ out)
{
    __shared__ float txt[4][512];
    __shared__ float ssn[2][512];
    __shared__ float sln[2][512];
    __shared__ float red[512];
    __shared__ float lg[8];
    int t = threadIdx.x;

    auto reduceSum = [&](float v) -> float {
        red[t] = v; __syncthreads();
        for (int s = 256; s; s >>= 1) { if (t < s) red[t] += red[t + s]; __syncthreads(); }
        float r = red[0]; __syncthreads();
        return r;
    };

    for (int c = 0; c < 4; ++c) {
        float m = -1e30f;
        for (int k = 0; k < 8; ++k) m = fmaxf(m, desc[((size_t)c * 8 + k) * 512 + t]);
        float ss = reduceSum(m * m);
        txt[c][t] = m / fmaxf(sqrtf(ss), EPS_);
    }
    for (int b = 0; b < 2; ++b) {
        float v = slide_s[b * 512 + t];
        float ss = reduceSum(v * v);
        ssn[b][t] = v / fmaxf(sqrtf(ss), EPS_);
        v = slide_l[b * 512 + t];
        ss = reduceSum(v * v);
        sln[b][t] = v / fmaxf(sqrtf(ss), EPS_);
    }
    __syncthreads();
    for (int b = 0; b < 2; ++b)
        for (int c = 0; c < 4; ++c) {
            float v = ssn[b][t] * txt[c][t] + sln[b][t] * txt[c][t];
            float s = reduceSum(v);
            if (t == 0) lg[b * 4 + c] = s;
        }
    __syncthreads();
    if (t < 2) {
        int b = t;
        float m = -1e30f;
        for (int c = 0; c < 4; ++c) m = fmaxf(m, lg[b * 4 + c]);
        float e[4]; float den = 0.f;
        for (int c = 0; c < 4; ++c) { e[c] = expf(lg[b * 4 + c] - m); den += e[c]; }
        int am = 0; float bm = -1.f;
        for (int c = 0; c < 4; ++c) {
            float pcl = e[c] / den;
            out[b * 4 + c] = pcl;
            if (pcl > bm) { bm = pcl; am = c; }
        }
        out[8 + b] = (float)am;
    }
}

extern "C" void kernel_launch(void* const* d_in, const int* in_sizes, int n_in,
                              void* d_out, int out_size, void* d_ws, size_t ws_size,
                              hipStream_t stream) {
    const float* x_s    = (const float*)d_in[0];
    const float* x_l    = (const float*)d_in[2];
    const float* W_proj = (const float*)d_in[4];
    const float* b_proj = (const float*)d_in[5];
    const float* desc   = (const float*)d_in[6];
    const float* Wv     = (const float*)d_in[7];
    const float* bv     = (const float*)d_in[8];
    const float* Wu     = (const float*)d_in[9];
    const float* bu     = (const float*)d_in[10];
    const float* w_attn = (const float*)d_in[11];
    float* out = (float*)d_out;

    // workspace layout (bytes):
    //  0         : xn    bf16 [65536x512]  (67108864)
    //  67108864  : xpraw bf16 [65536x512]  (67108864)
    //  134217728 : WpT   bf16 [512x512]    (524288)
    //  134742016 : WvuT  bf16 [512x512]    (524288, fine-interleaved)
    //  135266304 : descF bf16 fragment     (32768)
    //  135299072 : bvu   f32 [512]         (2048)
    //  135301120 : invn  f32 [65536]       (262144)
    //  135563264 : Araw  f32 [65536]       (262144)
    //  135825408 : part  f32 [4x32x2]      (1024)
    //  135826432 : mg    f32 [4x2]         (32, padded)
    //  135827456 : slideAll f32 [4x512]    (8192)
    char* w = (char*)d_ws;
    u16* xn        = (u16*)w;
    u16* xpraw     = (u16*)(w + 67108864);
    u16* WpT       = (u16*)(w + 134217728);
    u16* WvuT      = (u16*)(w + 134742016);
    u16* descF     = (u16*)(w + 135266304);
    float* bvu     = (float*)(w + 135299072);
    float* invn    = (float*)(w + 135301120);
    float* Araw    = (float*)(w + 135563264);
    float* part    = (float*)(w + 135825408);
    float* mg      = (float*)(w + 135826432);
    float* slideAll= (float*)(w + 135827456);

    hipMemsetAsync(slideAll, 0, 8192, stream);
    prep_weights_kernel<<<1024, 256, 0, stream>>>(W_proj, Wv, Wu, bv, bu, desc,
                                                  WpT, WvuT, bvu, descF);

    rownorm_cast_kernel<<<ROWS2 / 4, 256, 0, stream>>>(x_s, x_l, xn);
    gemm_bias_kernel<<<512, 512, 0, stream>>>(xn, WpT, b_proj, xpraw);
    gatecls_kernel<<<512, 512, 0, stream>>>(xpraw, WvuT, descF, bvu, w_attn,
                                            invn, Araw, out + 10);
    areduce_kernel<<<dim3(32, 4), 256, 0, stream>>>(Araw, part);
    acombine_kernel<<<1, 128, 0, stream>>>(part, mg);
    pool_kernel<<<dim3(64, 4), 256, 0, stream>>>(Araw, invn, mg, xpraw, slideAll);
    finalize_kernel<<<1, 512, 0, stream>>>(slideAll, slideAll + 1024, desc, out);
}